// Round 1
// baseline (119.369 us; speedup 1.0000x reference)
//
#include <hip/hip_runtime.h>

#define BB  16
#define SS  2048
#define DD  64
#define OO  128

// ---------------------------------------------------------------------------
// Kernel 1: Y[b,o,d] = sum_t W[o,t] * X[b,t,d]
// grid = B(16) * o_tiles(16) * t_splits(4) = 1024 blocks, 256 threads.
// Each block: 8 consecutive o, 512-wide t-range, full d=64.
// ---------------------------------------------------------------------------
__global__ __launch_bounds__(256) void k_y(const float* __restrict__ X,
                                           const float* __restrict__ W,
                                           float* __restrict__ Y) {
    const int bx  = blockIdx.x;
    const int tsp = bx & 3;          // t split 0..3
    const int ot  = (bx >> 2) & 15;  // o tile 0..15
    const int b   = bx >> 6;         // batch 0..15
    const int tid = threadIdx.x;
    const int d   = tid & 63;
    // force wave-uniformity so W loads become s_load (wave = 64 lanes)
    const int g   = __builtin_amdgcn_readfirstlane(tid >> 6);  // 0..3

    const float* Xb = X + (size_t)b * SS * DD;
    const float* Wr = W + (size_t)(ot * 8) * SS;

    float acc[8];
#pragma unroll
    for (int j = 0; j < 8; ++j) acc[j] = 0.f;

    const int t0 = tsp * 512;
#pragma unroll 4
    for (int t = t0 + g; t < t0 + 512; t += 4) {
        const float xv = Xb[(size_t)t * DD + d];  // 256B coalesced per wave
#pragma unroll
        for (int j = 0; j < 8; ++j)
            acc[j] += Wr[(size_t)j * SS + t] * xv;  // wave-uniform -> s_load
    }

    __shared__ float red[4][8][64];
#pragma unroll
    for (int j = 0; j < 8; ++j) red[g][j][d] = acc[j];
    __syncthreads();

    for (int u = tid; u < 512; u += 256) {
        const int j  = u >> 6;
        const int dd = u & 63;
        const float s = red[0][j][dd] + red[1][j][dd] +
                        red[2][j][dd] + red[3][j][dd];
        atomicAdd(&Y[((size_t)b * OO + ot * 8 + j) * DD + dd], s);
    }
}

// ---------------------------------------------------------------------------
// Kernel 2: out[b,s,o] = sum_d X[b,s,d] * Y[b,o,d] + bias[o]
// grid = B(16) * s_tiles(32) = 512 blocks, 256 threads.
// LDS: X tile 64x64 (16KB) + Y[b] 128x64 (32KB), XOR-swizzled 16B chunks so
// ds_read_b128 stays 16B-aligned with <=2-way bank aliasing (free on wave64).
// Each thread: 4(s) x 8(o) register tile, K=64 inner product.
// ---------------------------------------------------------------------------
__device__ __forceinline__ int swz(int row, int dc) {  // float index of chunk
    return row * 64 + (((dc ^ (row >> 3)) & 15) << 2);
}

__global__ __launch_bounds__(256) void k_out(const float* __restrict__ X,
                                             const float* __restrict__ Y,
                                             const float* __restrict__ bias,
                                             float* __restrict__ out) {
    __shared__ float Xl[64 * 64];
    __shared__ float Yl[128 * 64];

    const int bx  = blockIdx.x;
    const int b   = bx >> 5;
    const int s0  = (bx & 31) * 64;
    const int tid = threadIdx.x;

    const float* Xt = X + ((size_t)b * SS + s0) * DD;  // 4096 contiguous floats
    const float* Yb = Y + (size_t)b * OO * DD;         // 8192 contiguous floats

    // stage X tile (4 float4 / thread)
#pragma unroll
    for (int i = 0; i < 4; ++i) {
        const int f = (tid + 256 * i) * 4;
        const float4 v = *(const float4*)(Xt + f);
        const int s  = f >> 6;
        const int dc = (f >> 2) & 15;
        *(float4*)&Xl[swz(s, dc)] = v;
    }
    // stage Y[b] (8 float4 / thread)
#pragma unroll
    for (int i = 0; i < 8; ++i) {
        const int f = (tid + 256 * i) * 4;
        const float4 v = *(const float4*)(Yb + f);
        const int o  = f >> 6;
        const int dc = (f >> 2) & 15;
        *(float4*)&Yl[swz(o, dc)] = v;
    }

    const int to = tid & 15;   // o-tile 8 wide
    const int ts = tid >> 4;   // s-tile 4 wide

    const float4 bv0 = *(const float4*)(bias + to * 8);
    const float4 bv1 = *(const float4*)(bias + to * 8 + 4);

    float acc[4][8];
#pragma unroll
    for (int i = 0; i < 4; ++i) {
        acc[i][0] = bv0.x; acc[i][1] = bv0.y; acc[i][2] = bv0.z; acc[i][3] = bv0.w;
        acc[i][4] = bv1.x; acc[i][5] = bv1.y; acc[i][6] = bv1.z; acc[i][7] = bv1.w;
    }

    __syncthreads();

#pragma unroll 4
    for (int dc = 0; dc < 16; ++dc) {
        float4 xv[4], yv[8];
#pragma unroll
        for (int i = 0; i < 4; ++i)
            xv[i] = *(const float4*)&Xl[swz(ts * 4 + i, dc)];
#pragma unroll
        for (int j = 0; j < 8; ++j)
            yv[j] = *(const float4*)&Yl[swz(to * 8 + j, dc)];
#pragma unroll
        for (int i = 0; i < 4; ++i)
#pragma unroll
            for (int j = 0; j < 8; ++j) {
                acc[i][j] += xv[i].x * yv[j].x;
                acc[i][j] += xv[i].y * yv[j].y;
                acc[i][j] += xv[i].z * yv[j].z;
                acc[i][j] += xv[i].w * yv[j].w;
            }
    }

    float* op = out + ((size_t)b * SS + s0 + ts * 4) * OO + to * 8;
#pragma unroll
    for (int i = 0; i < 4; ++i) {
        *(float4*)(op + (size_t)i * OO)     = make_float4(acc[i][0], acc[i][1], acc[i][2], acc[i][3]);
        *(float4*)(op + (size_t)i * OO + 4) = make_float4(acc[i][4], acc[i][5], acc[i][6], acc[i][7]);
    }
}

extern "C" void kernel_launch(void* const* d_in, const int* in_sizes, int n_in,
                              void* d_out, int out_size, void* d_ws, size_t ws_size,
                              hipStream_t stream) {
    const float* X    = (const float*)d_in[0];  // [B,S,D]
    const float* W    = (const float*)d_in[1];  // [OUT,S]
    const float* bias = (const float*)d_in[2];  // [OUT]
    float* out = (float*)d_out;                 // [B,S,OUT]
    float* Y   = (float*)d_ws;                  // [B,OUT,D] = 512KB scratch

    hipMemsetAsync(d_ws, 0, (size_t)BB * OO * DD * sizeof(float), stream);
    k_y<<<dim3(1024), dim3(256), 0, stream>>>(X, W, Y);
    k_out<<<dim3(512), dim3(256), 0, stream>>>(X, Y, bias, out);
}